// Round 7
// baseline (397.577 us; speedup 1.0000x reference)
//
#include <hip/hip_runtime.h>
#include <hip/hip_bf16.h>

#define N 8192
#define IN_F 128
#define OUT_F 64
#define LRELU_ALPHA 0.2f
#define CH 1024   // columns per pipeline iteration
#define NIT 8     // N / CH
#define PSTR 1040 // shorts per LDS p-row (1024 + 16: breaks pow2, keeps 16B align)

typedef __attribute__((ext_vector_type(8))) short short8;
typedef __attribute__((ext_vector_type(4))) float float4v;
typedef __attribute__((ext_vector_type(4))) unsigned short ushortx4;

__device__ __forceinline__ unsigned short bf16_bits(float x) {
  unsigned u = __builtin_bit_cast(unsigned, x);
  u += 0x7fffu + ((u >> 16) & 1u);  // round-to-nearest-even
  return (unsigned short)(u >> 16);
}

// prep: Wh = h@W (fp32), s1 = Wh@a1, s2 = Wh@a2, whT bf16 [64][8192]
__global__ __launch_bounds__(256) void prep_kernel(
    const float* __restrict__ h, const float* __restrict__ W,
    const float* __restrict__ a, float* __restrict__ s1,
    float* __restrict__ s2, unsigned short* __restrict__ whT) {
  const int tid = threadIdx.x;
  const int row = blockIdx.x * 4 + (tid >> 6);
  const int k = tid & 63;
  const float* hr = h + row * IN_F;
  float acc = 0.f;
#pragma unroll 8
  for (int c = 0; c < IN_F; ++c) acc = fmaf(hr[c], W[c * OUT_F + k], acc);
  whT[(long)k * N + row] = bf16_bits(acc);
  float p1 = acc * a[k];
  float p2 = acc * a[OUT_F + k];
#pragma unroll
  for (int off = 32; off > 0; off >>= 1) {
    p1 += __shfl_xor(p1, off);
    p2 += __shfl_xor(p2, off);
  }
  if (k == 0) { s1[row] = p1; s2[row] = p2; }
}

// repack whT [64][8192] -> B-fragment order: whF[(c32*256 + tt*64 + lane)*8]
// lane=(quad,r16): holds Wh[node=c32*32+quad*8+j][dim=tt*16+r16], j=0..7.
__global__ __launch_bounds__(256) void repack_kernel(
    const unsigned short* __restrict__ whT, unsigned short* __restrict__ whF) {
  const int f = blockIdx.x * 256 + threadIdx.x;  // 0..65535 fragments
  const int lane = f & 63, tt = (f >> 6) & 3, c = f >> 8;
  const int r16 = lane & 15, quad = lane >> 4;
  const short8 v = *(const short8*)(whT + (long)(tt * 16 + r16) * N + c * 32 + quad * 8);
  *(short8*)(whF + (long)f * 8) = v;
}

__device__ __forceinline__ void p_write(unsigned short* pr, int c, int4 av,
                                        float4 s2v, float s1w) {
  float e0 = s1w + s2v.x; e0 = fmaxf(e0, LRELU_ALPHA * e0);
  float e1 = s1w + s2v.y; e1 = fmaxf(e1, LRELU_ALPHA * e1);
  float e2 = s1w + s2v.z; e2 = fmaxf(e2, LRELU_ALPHA * e2);
  float e3 = s1w + s2v.w; e3 = fmaxf(e3, LRELU_ALPHA * e3);
  const float p0 = av.x > 0 ? __expf(e0) : 0.f;
  const float p1 = av.y > 0 ? __expf(e1) : 0.f;
  const float p2 = av.z > 0 ? __expf(e2) : 0.f;
  const float p3 = av.w > 0 ? __expf(e3) : 0.f;
  ushortx4 pk = {bf16_bits(p0), bf16_bits(p1), bf16_bits(p2), bf16_bits(p3)};
  *(ushortx4*)(pr + c) = pk;
}

// Fused GAT, depth-2 pipeline: 512 blocks x 1024 thr (16 waves = 16 rows).
// Wave w streams row row0+w of adj sequentially, 4KB per iter, with loads
// issued a FULL iteration before use (depth-2). p staged in double-buffered
// LDS [16][1024]; MFMA phase: wave w handles chunks it*32+w and it*32+16+w.
// Denominator via ones-B MFMA. 8 barriers total.
__global__ __launch_bounds__(1024, 4) void gat_kernel(
    const int* __restrict__ adj, const float* __restrict__ s1,
    const float* __restrict__ s2, const unsigned short* __restrict__ whF,
    float* __restrict__ out) {
  __shared__ __align__(16) unsigned short pbuf[2][16][PSTR];  // 66560 B
  const int tid = threadIdx.x;
  const int w = tid >> 6, L = tid & 63;
  const int r16 = L & 15, quad = L >> 4;
  const int row0 = blockIdx.x * 16;
  const long arow = (long)(row0 + w) * N;
  const float s1w = s1[row0 + w];  // wave-uniform

  float4v acc0 = {0.f, 0.f, 0.f, 0.f};
  float4v acc1 = {0.f, 0.f, 0.f, 0.f};
  float4v acc2 = {0.f, 0.f, 0.f, 0.f};
  float4v acc3 = {0.f, 0.f, 0.f, 0.f};
  float4v accD = {0.f, 0.f, 0.f, 0.f};
  const short ONE = (short)0x3F80;  // bf16 1.0
  const short8 ones = {ONE, ONE, ONE, ONE, ONE, ONE, ONE, ONE};

  int4 ra[4];
  float4 rs[4];
  // prologue: iter 0 loaded, p-written; iter 1 loads in flight
#pragma unroll
  for (int k = 0; k < 4; ++k) {
    ra[k] = *(const int4*)(adj + arow + k * 256 + L * 4);
    rs[k] = *(const float4*)(s2 + k * 256 + L * 4);
  }
#pragma unroll
  for (int k = 0; k < 4; ++k)
    p_write(pbuf[0][w], k * 256 + L * 4, ra[k], rs[k], s1w);
#pragma unroll
  for (int k = 0; k < 4; ++k) {
    ra[k] = *(const int4*)(adj + arow + CH + k * 256 + L * 4);
    rs[k] = *(const float4*)(s2 + CH + k * 256 + L * 4);
  }
  __syncthreads();

  for (int it = 0; it < NIT; ++it) {
    const int b = it & 1;
    if (it < NIT - 1) {
      // stage p for iter it+1 (regs loaded one full iter ago)
      unsigned short* pr = pbuf[b ^ 1][w];
#pragma unroll
      for (int k = 0; k < 4; ++k)
        p_write(pr, k * 256 + L * 4, ra[k], rs[k], s1w);
      if (it < NIT - 2) {  // issue loads for iter it+2 (depth-2 lookahead)
        const long base = arow + (long)(it + 2) * CH + L * 4;
        const int sbase = (it + 2) * CH + L * 4;
#pragma unroll
        for (int k = 0; k < 4; ++k) {
          ra[k] = *(const int4*)(adj + base + k * 256);
          rs[k] = *(const float4*)(s2 + sbase + k * 256);
        }
      }
    }
    // MFMA phase: this wave's two 32-col chunks of iter it
#pragma unroll
    for (int sub = 0; sub < 2; ++sub) {
      const int lc = (sub * 16 + w) * 32;  // col offset (shorts) within row
      const short8 afrag = *(const short8*)(&pbuf[b][r16][lc + quad * 8]);
      const int c32 = it * 32 + sub * 16 + w;
      const unsigned short* bp = whF + ((long)c32 * 256 + L) * 8;
      const short8 b0 = *(const short8*)(bp);
      const short8 b1 = *(const short8*)(bp + 512);
      const short8 b2 = *(const short8*)(bp + 1024);
      const short8 b3 = *(const short8*)(bp + 1536);
      acc0 = __builtin_amdgcn_mfma_f32_16x16x32_bf16(afrag, b0, acc0, 0, 0, 0);
      acc1 = __builtin_amdgcn_mfma_f32_16x16x32_bf16(afrag, b1, acc1, 0, 0, 0);
      acc2 = __builtin_amdgcn_mfma_f32_16x16x32_bf16(afrag, b2, acc2, 0, 0, 0);
      acc3 = __builtin_amdgcn_mfma_f32_16x16x32_bf16(afrag, b3, acc3, 0, 0, 0);
      accD = __builtin_amdgcn_mfma_f32_16x16x32_bf16(afrag, ones, accD, 0, 0, 0);
    }
    __syncthreads();
  }

  // merge 16 wave-partials in LDS (aliases pbuf; 8 slots x 1040 floats)
  float* M = (float*)pbuf;
  if (w >= 8) {
    float* S = M + (w - 8) * 1040;
#pragma unroll
    for (int reg = 0; reg < 4; ++reg) {
      const int r = quad * 4 + reg;  // C-layout: row=quad*4+reg, col=r16
      S[r * 64 + 0 * 16 + r16] = acc0[reg];
      S[r * 64 + 1 * 16 + r16] = acc1[reg];
      S[r * 64 + 2 * 16 + r16] = acc2[reg];
      S[r * 64 + 3 * 16 + r16] = acc3[reg];
      if (r16 == 0) S[1024 + r] = accD[reg];
    }
  }
  __syncthreads();
  if (w < 8) {
    float* S = M + w * 1040;
#pragma unroll
    for (int reg = 0; reg < 4; ++reg) {
      const int r = quad * 4 + reg;
      S[r * 64 + 0 * 16 + r16] += acc0[reg];
      S[r * 64 + 1 * 16 + r16] += acc1[reg];
      S[r * 64 + 2 * 16 + r16] += acc2[reg];
      S[r * 64 + 3 * 16 + r16] += acc3[reg];
      if (r16 == 0) S[1024 + r] += accD[reg];
    }
  }
  __syncthreads();
  {
    const int r = tid >> 6, k = tid & 63;
    float Sv = 0.f, Lv = 0.f;
#pragma unroll
    for (int s = 0; s < 8; ++s) {
      Sv += M[s * 1040 + r * 64 + k];
      Lv += M[s * 1040 + 1024 + r];
    }
    const float v = Sv / Lv;
    out[(long)(row0 + r) * OUT_F + k] = v > 0.f ? v : expm1f(v);
  }
}

extern "C" void kernel_launch(void* const* d_in, const int* in_sizes, int n_in,
                              void* d_out, int out_size, void* d_ws, size_t ws_size,
                              hipStream_t stream) {
  const float* h = (const float*)d_in[0];
  const int* adj = (const int*)d_in[1];
  const float* W = (const float*)d_in[2];
  const float* a = (const float*)d_in[3];
  float* out = (float*)d_out;

  // ws: s1[8192] | s2[8192] | whT[64*8192] bf16 | whF[64*8192] bf16 (~2.1MB)
  float* s1 = (float*)d_ws;
  float* s2 = s1 + N;
  unsigned short* whT = (unsigned short*)(s2 + N);
  unsigned short* whF = whT + (long)OUT_F * N;

  prep_kernel<<<N / 4, 256, 0, stream>>>(h, W, a, s1, s2, whT);
  repack_kernel<<<N * OUT_F / 8 / 256, 256, 0, stream>>>(whT, whF);
  gat_kernel<<<N / 16, 1024, 0, stream>>>(adj, s1, s2, whF, out);
}